// Round 7
// baseline (5115.612 us; speedup 1.0000x reference)
//
#include <hip/hip_runtime.h>
#include <math.h>

#define FF 2048
#define NL 12
#define NB 16
#define TT 32
#define EPS 1e-5f
#define LOG2E 1.44269504088896f

#if __has_builtin(__builtin_amdgcn_exp2f)
#define EXP2(x) __builtin_amdgcn_exp2f(x)
#else
#define EXP2(x) exp2f(x)
#endif

typedef float v2f __attribute__((ext_vector_type(2)));
__device__ __forceinline__ v2f mk2(float x){ v2f r; r.x = x; r.y = x; return r; }

// ---------------------------------------------------------------------------
// Prepack into d_ws as w_all[24][4096] float4, f-PAIRED for packed math.
// ---------------------------------------------------------------------------
__global__ __launch_bounds__(256) void prepack_kernel(
    const float* __restrict__ enc_l1_w, const float* __restrict__ enc_l1_b,
    const float* __restrict__ enc_l2_w,
    const float* __restrict__ dec_l1_w, const float* __restrict__ dec_l1_b,
    const float* __restrict__ dec_l2_w,
    float4* __restrict__ w_all)
{
    int idx = blockIdx.x * blockDim.x + threadIdx.x;
    if (idx >= 24 * 1024) return;
    int lay = idx >> 10;
    int fp  = idx & 1023;
    int f0  = 2*fp, f1 = 2*fp + 1;
    const float *w1, *b1, *w2;
    if (lay < NL) {
        w1 = enc_l1_w + (size_t)lay * FF * 3;
        b1 = enc_l1_b + (size_t)lay * FF;
        w2 = enc_l2_w + (size_t)lay * 3 * FF;
    } else {
        int l = lay - NL;
        w1 = dec_l1_w + (size_t)l * FF * 3;
        b1 = dec_l1_b + (size_t)l * FF;
        w2 = dec_l2_w + (size_t)l * 3 * FF;
    }
    float4* base = w_all + (size_t)lay * 4096;
    base[fp]        = make_float4(w1[f0*3+0], w1[f1*3+0], w1[f0*3+1], w1[f1*3+1]);
    base[1024 + fp] = make_float4(w1[f0*3+2], w1[f1*3+2], b1[f0],     b1[f1]);
    base[2048 + fp] = make_float4(w2[f0],     w2[f1],     w2[FF+f0],  w2[FF+f1]);
    base[3072 + fp] = make_float4(w2[2*FF+f0], w2[2*FF+f1], 0.f, 0.f);
}

// ---------------------------------------------------------------------------
// One block per TWO batch elements, 1024 threads (16 waves), 4-slot pairing:
//   s0: P1(e0,g)  | FFNhalfA(e1,g-1) |            barrier
//   s1: P2(e0,g)  | FFNhalfB(e1,g-1) |            barrier
//   s2: P1(e1,g)  | FFNhalfA(e0,g)   | stage h0   barrier
//   s3: P2(e1,g)  | FFNhalfB(e0,g)   | stage h1   barrier
// x4 is ELIMINATED: both P1 (residual/combine) and the FFN (X load)
// recompute the FFN-input X inline from bb4 + oo2 (CAPROJ formula), which
// removes the P3 slot and makes the pairing collision-free. FFN halves are
// token-split and fully self-contained (no cross-barrier register state).
// Attention is 3-wave per-head parallel (R0-verified); decoder outputs live
// redundantly in each attn wave's O registers.
// ---------------------------------------------------------------------------
struct __align__(16) SharedMem {
    float4 wbuf[2][4096];      // double-buffered layer weights (128 KB)
    float4 bb4[2][TT];         // post-LN1 B per element (SA block output)
    float4 oo[2][TT];          // SA attention outputs {h0,h1,h2,-}
    float4 oo2[2][TT];         // CA attention outputs
    float  fred[2][TT][3][3];  // FFN partials: 3 per (elem, token, dim)
    float  kk[2][3][TT];       // self-attn keys, head-major
    float  vv[2][3][TT];       // self-attn values
    float  cak[2][3][TT];      // cross-attn keys (recomputed per layer)
    float  cav[2][3][TT];      // cross-attn values
};

__device__ __forceinline__ void ln3s(float y0, float y1, float y2,
    const float* __restrict__ w, const float* __restrict__ b,
    float& o0, float& o1, float& o2)
{
    float m  = (y0 + y1 + y2) * (1.0f / 3.0f);
    float d0 = y0 - m, d1 = y1 - m, d2 = y2 - m;
    float v  = (d0*d0 + d1*d1 + d2*d2) * (1.0f / 3.0f);
    float r  = __builtin_amdgcn_rsqf(v + EPS);
    o0 = d0 * r * w[0] + b[0];
    o1 = d1 * r * w[1] + b[1];
    o2 = d2 * r * w[2] + b[2];
}

template<int CTRL>
__device__ __forceinline__ float dpp_add(float v)
{
    int sh = __builtin_amdgcn_update_dpp(0, __float_as_int(v), CTRL, 0xF, 0xF, true);
    return v + __int_as_float(sh);
}

__device__ __forceinline__ float wave_sum64(float v)
{
    v = dpp_add<0x111>(v);
    v = dpp_add<0x112>(v);
    v = dpp_add<0x114>(v);
    v = dpp_add<0x118>(v);
    v = dpp_add<0x142>(v);
    v = dpp_add<0x143>(v);
    return v;   // valid in lane 63
}

__device__ __forceinline__ float fr3(const float* p) { return p[0] + p[1] + p[2]; }

// FFN-input X of layer L, token t, element e, from bb4 (+ CA proj for dec).
__device__ __forceinline__ void xfrom(const SharedMem& s, int e, int t, int L,
    const float* __restrict__ dec_ca_ow, const float* __restrict__ dec_ca_ob,
    const float* __restrict__ dec_n2_w, const float* __restrict__ dec_n2_b,
    float& X0, float& X1, float& X2)
{
    float4 bb = s.bb4[e][t];
    if (L < 12) { X0 = bb.x; X1 = bb.y; X2 = bb.z; }
    else {
        const int ip = (L - 12) % 12;
        float4 c2 = s.oo2[e][t];
        const float* caow = dec_ca_ow + ip*9;
        const float* caob = dec_ca_ob + ip*3;
        float y0 = bb.x + caob[0] + caow[0]*c2.x + caow[1]*c2.y + caow[2]*c2.z;
        float y1 = bb.y + caob[1] + caow[3]*c2.x + caow[4]*c2.y + caow[5]*c2.z;
        float y2 = bb.z + caob[2] + caow[6]*c2.x + caow[7]*c2.y + caow[8]*c2.z;
        ln3s(y0, y1, y2, dec_n2_w + ip*3, dec_n2_b + ip*3, X0, X1, X2);
    }
}

// Halved-range softmax-attention (R0-proven). lanes 0-31: keys 0..15,
// lanes 32-63: keys 16..31; combine via shfl_xor(32). qs has log2e folded.
template<bool MASK>
__device__ __forceinline__ float attn_half(float qs,
    const float* __restrict__ k, const float* __restrict__ v,
    int half, int ntok, int rep, float repw)
{
    const float4* k4 = (const float4*)k;
    const float4* v4 = (const float4*)v;
    float den0 = 0.f, den1 = 0.f, nv0 = 0.f, nv1 = 0.f;
    #pragma unroll
    for (int jb = 0; jb < 4; ++jb) {
        const int jbase = half*16 + jb*4;
        if (!MASK || jbase < ntok) {
            float4 kq = k4[half*4 + jb];
            float4 vq = v4[half*4 + jb];
            const float kj[4] = {kq.x, kq.y, kq.z, kq.w};
            const float vj[4] = {vq.x, vq.y, vq.z, vq.w};
            #pragma unroll
            for (int u = 0; u < 4; ++u) {
                float w = EXP2(qs * kj[u]);
                if (MASK) {
                    const int j = jbase + u;
                    w = (j < ntok) ? w : 0.f;
                    w = (j == rep) ? w * repw : w;
                }
                if (jb & 1) { den1 += w; nv1 = fmaf(w, vj[u], nv1); }
                else        { den0 += w; nv0 = fmaf(w, vj[u], nv0); }
            }
        }
    }
    float den = den0 + den1;
    float nv  = nv0 + nv1;
    den += __shfl_xor(den, 32, 64);
    nv  += __shfl_xor(nv , 32, 64);
    return nv * __builtin_amdgcn_rcpf(den);
}

// One f-pair column step of the FFN for NII tokens.
template<int NII>
__device__ __forceinline__ void ffn_jp(const float4* __restrict__ wb, int fp,
    const float (&X0)[NII], const float (&X1)[NII], const float (&X2)[NII],
    v2f (&a0)[NII], v2f (&a1)[NII], v2f (&a2)[NII])
{
    float4 A0 = wb[fp], A1 = wb[1024+fp];
    float4 C0 = wb[2048+fp], C1 = wb[3072+fp];
    v2f ax = {A0.x, A0.y}, ay = {A0.z, A0.w};
    v2f az = {A1.x, A1.y}, ab = {A1.z, A1.w};
    v2f cx = {C0.x, C0.y}, cy = {C0.z, C0.w};
    v2f cz = {C1.x, C1.y};
    const v2f z2 = {0.f, 0.f};
    #pragma unroll
    for (int ii = 0; ii < NII; ++ii) {
        v2f h2 = __builtin_elementwise_fma(ax, mk2(X0[ii]),
                 __builtin_elementwise_fma(ay, mk2(X1[ii]),
                 __builtin_elementwise_fma(az, mk2(X2[ii]), ab)));
        h2 = __builtin_elementwise_max(h2, z2);
        a0[ii] = __builtin_elementwise_fma(cx, h2, a0[ii]);
        a1[ii] = __builtin_elementwise_fma(cy, h2, a1[ii]);
        a2[ii] = __builtin_elementwise_fma(cz, h2, a2[ii]);
    }
}

// Self-contained FFN half over tokens {gi+4*(ii0+ii)}: X computed inline
// from bb4/oo2 (xfrom), all 1024/192 columns, reduce, store fred.
template<int NII>
__device__ __forceinline__ void ffn_pass(SharedMem& s, int e,
    const float4* __restrict__ wb, int L, int gi, int w3, int flane, int lane,
    int ii0,
    const float* __restrict__ dec_ca_ow, const float* __restrict__ dec_ca_ob,
    const float* __restrict__ dec_n2_w, const float* __restrict__ dec_n2_b)
{
    const v2f z2 = {0.f, 0.f};
    float X0[NII], X1[NII], X2[NII];
    v2f a0[NII], a1[NII], a2[NII];
    #pragma unroll
    for (int ii = 0; ii < NII; ++ii) {
        const int t = gi + 4*(ii0 + ii);
        xfrom(s, e, t, L, dec_ca_ow, dec_ca_ob, dec_n2_w, dec_n2_b,
              X0[ii], X1[ii], X2[ii]);
        a0[ii] = z2; a1[ii] = z2; a2[ii] = z2;
    }
    #pragma unroll
    for (int jp = 0; jp < 5; ++jp)
        ffn_jp<NII>(wb, flane + 192*jp, X0, X1, X2, a0, a1, a2);
    if (flane < 64)
        ffn_jp<NII>(wb, flane + 960, X0, X1, X2, a0, a1, a2);
    #pragma unroll
    for (int ii = 0; ii < NII; ++ii) {
        const int t = gi + 4*(ii0 + ii);
        float r0 = wave_sum64(a0[ii].x + a0[ii].y);
        float r1 = wave_sum64(a1[ii].x + a1[ii].y);
        float r2 = wave_sum64(a2[ii].x + a2[ii].y);
        if (lane == 63) {
            s.fred[e][t][0][w3] = r0;
            s.fred[e][t][1][w3] = r1;
            s.fred[e][t][2][w3] = r2;
        }
    }
}

__global__ __launch_bounds__(1024, 4) void seq_kernel(
    const float* __restrict__ src, const float* __restrict__ angle,
    const float* __restrict__ enc_sa_w, const float* __restrict__ enc_sa_b,
    const float* __restrict__ enc_sa_ow, const float* __restrict__ enc_sa_ob,
    const float* __restrict__ enc_l2_b,
    const float* __restrict__ enc_n1_w, const float* __restrict__ enc_n1_b,
    const float* __restrict__ enc_n2_w, const float* __restrict__ enc_n2_b,
    const float* __restrict__ enc_nf_w, const float* __restrict__ enc_nf_b,
    const float* __restrict__ dec_sa_w, const float* __restrict__ dec_sa_b,
    const float* __restrict__ dec_sa_ow, const float* __restrict__ dec_sa_ob,
    const float* __restrict__ dec_ca_w, const float* __restrict__ dec_ca_b,
    const float* __restrict__ dec_ca_ow, const float* __restrict__ dec_ca_ob,
    const float* __restrict__ dec_l2_b,
    const float* __restrict__ dec_n1_w, const float* __restrict__ dec_n1_b,
    const float* __restrict__ dec_n2_w, const float* __restrict__ dec_n2_b,
    const float* __restrict__ dec_n3_w, const float* __restrict__ dec_n3_b,
    const float* __restrict__ dec_nf_w, const float* __restrict__ dec_nf_b,
    const float4* __restrict__ w_all,
    float* __restrict__ out)
{
    __shared__ SharedMem s;
    const int tid  = threadIdx.x;
    const int b0   = blockIdx.x * 2;
    const int wv   = tid >> 6;
    const int lane = tid & 63;
    const int q    = lane & 31;
    const int half = lane >> 5;

    // ---- init: stage encoder layer 0 weights
    for (int k = tid; k < 4096; k += 1024)
        s.wbuf[0][k] = w_all[k];

    // attn-wave registers per element: embeds, decode outputs, enc memory
    float EA0=0.f,EA1=0.f,EA2=0.f, EB0=0.f,EB1=0.f,EB2=0.f;
    float OA0=0.f,OA1=0.f,OA2=0.f, OB0=0.f,OB1=0.f,OB2=0.f;
    float MA0=0.f,MA1=0.f,MA2=0.f, MB0=0.f,MB1=0.f,MB2=0.f;
    if (wv < 3) {
        EA0 = src[b0*64 + q];       EA1 = src[b0*64 + 32 + q];       EA2 = angle[b0];
        EB0 = src[(b0+1)*64 + q];   EB1 = src[(b0+1)*64 + 32 + q];   EB2 = angle[b0+1];
    }
    __syncthreads();

    float X0=0.f, X1=0.f, X2=0.f;        // attn: P1 -> P2 carry

    const int fw    = wv - 3;            // FFN wave index (valid wv 3..14)
    const int gi    = fw & 3;
    const int w3    = fw >> 2;
    const int flane = w3*64 + lane;

    // ------ P1: combine (X inline from bb4/oo2) + SA (+dec CA K/V) -> oo ------
    auto P1 = [&](int g, int e, float& M0, float& M1, float& M2,
                  float& Oa, float& Ob, float& Oc,
                  float Ea, float Eb, float Ec) {
        const int h = wv;
        __builtin_amdgcn_s_setprio(1);
        if (g == 0) { X0 = Ea; X1 = Eb; X2 = Ec; }
        else {
            float Xp0, Xp1, Xp2;
            xfrom(s, e, q, g-1, dec_ca_ow, dec_ca_ob, dec_n2_w, dec_n2_b,
                  Xp0, Xp1, Xp2);
            float f0 = fr3(s.fred[e][q][0]);
            float f1 = fr3(s.fred[e][q][1]);
            float f2 = fr3(s.fred[e][q][2]);
            if (g < 12) {
                ln3s(Xp0 + f0 + enc_l2_b[(g-1)*3+0],
                     Xp1 + f1 + enc_l2_b[(g-1)*3+1],
                     Xp2 + f2 + enc_l2_b[(g-1)*3+2],
                     enc_n2_w + (g-1)*3, enc_n2_b + (g-1)*3, X0, X1, X2);
            } else if (g == 12) {
                float o0, o1, o2;
                ln3s(Xp0 + f0 + enc_l2_b[33], Xp1 + f1 + enc_l2_b[34],
                     Xp2 + f2 + enc_l2_b[35], enc_n2_w + 33, enc_n2_b + 33,
                     o0, o1, o2);
                ln3s(o0, o1, o2, enc_nf_w, enc_nf_b, M0, M1, M2);
                Oa = (q == 0) ? Ea : 0.f;
                Ob = (q == 0) ? Eb : 0.f;
                Oc = (q == 0) ? Ec : 0.f;
                X0 = Oa; X1 = Ob; X2 = Oc;
            } else {
                const int t = 1 + (g - 12) / 12;
                const int i = (g - 12) % 12;
                if (i == 0) {
                    if (q == t-1) {
                        float o0, o1, o2;
                        ln3s(Xp0 + f0 + dec_l2_b[33], Xp1 + f1 + dec_l2_b[34],
                             Xp2 + f2 + dec_l2_b[35], dec_n3_w + 33, dec_n3_b + 33,
                             o0, o1, o2);
                        ln3s(o0, o1, o2, dec_nf_w, dec_nf_b, Oa, Ob, Oc);
                    }
                    const bool rl = (q <= t-1);
                    X0 = rl ? Oa : 0.f; X1 = rl ? Ob : 0.f; X2 = rl ? Oc : 0.f;
                } else {
                    ln3s(Xp0 + f0 + dec_l2_b[(i-1)*3+0],
                         Xp1 + f1 + dec_l2_b[(i-1)*3+1],
                         Xp2 + f2 + dec_l2_b[(i-1)*3+2],
                         dec_n3_w + (i-1)*3, dec_n3_b + (i-1)*3, X0, X1, X2);
                }
            }
        }
        if (g < 12) {
            const float* saw = enc_sa_w + g*27;
            const float* sab = enc_sa_b + g*9;
            if (lane < 32) {
                s.kk[e][h][q] = sab[3+h] + saw[9+3*h]*X0  + saw[10+3*h]*X1 + saw[11+3*h]*X2;
                s.vv[e][h][q] = sab[6+h] + saw[18+3*h]*X0 + saw[19+3*h]*X1 + saw[20+3*h]*X2;
            }
            float qv = (sab[h] + saw[3*h]*X0 + saw[3*h+1]*X1 + saw[3*h+2]*X2) * LOG2E;
            float o = attn_half<false>(qv, &s.kk[e][h][0], &s.vv[e][h][0], half, TT, -1, 1.f);
            if (lane < 32) ((float*)&s.oo[e][q])[h] = o;
        } else {
            const int t = 1 + (g - 12) / 12;
            const int i = (g - 12) % 12;
            const int ntok = t + 1;
            const float* saw = dec_sa_w + i*27;
            const float* sab = dec_sa_b + i*9;
            const float* caw = dec_ca_w + i*27;
            const float* cab = dec_ca_b + i*9;
            if (lane < 32) {
                if (q < ntok) {
                    s.kk[e][h][q] = sab[3+h] + saw[9+3*h]*X0  + saw[10+3*h]*X1 + saw[11+3*h]*X2;
                    s.vv[e][h][q] = sab[6+h] + saw[18+3*h]*X0 + saw[19+3*h]*X1 + saw[20+3*h]*X2;
                }
                s.cak[e][h][q] = cab[3+h] + caw[(3+h)*3]*M0 + caw[(3+h)*3+1]*M1 + caw[(3+h)*3+2]*M2;
                s.cav[e][h][q] = cab[6+h] + caw[(6+h)*3]*M0 + caw[(6+h)*3+1]*M1 + caw[(6+h)*3+2]*M2;
            }
            float qv = (sab[h] + saw[3*h]*X0 + saw[3*h+1]*X1 + saw[3*h+2]*X2) * LOG2E;
            float o = attn_half<true>(qv, &s.kk[e][h][0], &s.vv[e][h][0],
                                      half, ntok, t, (float)(TT - t));
            if (lane < 32 && q < ntok) ((float*)&s.oo[e][q])[h] = o;
        }
        __builtin_amdgcn_s_setprio(0);
    };

    // ------ P2: SA out-proj + LN1 -> bb4; decoder: CA -> oo2 ------
    auto P2 = [&](int g, int e) {
        const int h = wv;
        __builtin_amdgcn_s_setprio(1);
        float4 ov = s.oo[e][q];
        if (g < 12) {
            const float* saow = enc_sa_ow + g*9;
            const float* saob = enc_sa_ob + g*3;
            float y0 = X0 + saob[0] + saow[0]*ov.x + saow[1]*ov.y + saow[2]*ov.z;
            float y1 = X1 + saob[1] + saow[3]*ov.x + saow[4]*ov.y + saow[5]*ov.z;
            float y2 = X2 + saob[2] + saow[6]*ov.x + saow[7]*ov.y + saow[8]*ov.z;
            float B0, B1, B2;
            ln3s(y0, y1, y2, enc_n1_w + g*3, enc_n1_b + g*3, B0, B1, B2);
            if (h == 0 && lane < 32)
                s.bb4[e][q] = make_float4(B0, B1, B2, 0.f);
        } else {
            const int t = 1 + (g - 12) / 12;
            const int i = (g - 12) % 12;
            const int ntok = t + 1;
            const float* saow = dec_sa_ow + i*9;
            const float* saob = dec_sa_ob + i*3;
            float y0 = X0 + saob[0] + saow[0]*ov.x + saow[1]*ov.y + saow[2]*ov.z;
            float y1 = X1 + saob[1] + saow[3]*ov.x + saow[4]*ov.y + saow[5]*ov.z;
            float y2 = X2 + saob[2] + saow[6]*ov.x + saow[7]*ov.y + saow[8]*ov.z;
            float B0, B1, B2;
            ln3s(y0, y1, y2, dec_n1_w + i*3, dec_n1_b + i*3, B0, B1, B2);
            if (h == 0 && lane < 32 && q < ntok)
                s.bb4[e][q] = make_float4(B0, B1, B2, 0.f);
            const float* caw = dec_ca_w + i*27;
            const float* cab = dec_ca_b + i*9;
            float cqv = (cab[h] + caw[3*h]*B0 + caw[3*h+1]*B1 + caw[3*h+2]*B2) * LOG2E;
            float oc = attn_half<false>(cqv, &s.cak[e][h][0], &s.cav[e][h][0],
                                        half, TT, -1, 1.f);
            if (lane < 32 && q < ntok) ((float*)&s.oo2[e][q])[h] = oc;
        }
        __builtin_amdgcn_s_setprio(0);
    };

    // ------ FFN half hf for (layer L, element e) ------
    auto FFNH = [&](int L, int e, int hf) {
        const int ntokF = (L < 12) ? TT : (2 + (L - 12) / 12);
        const float4* wb = s.wbuf[L & 1];
        if (ntokF <= 8)
            ffn_pass<1>(s, e, wb, L, gi, w3, flane, lane, hf,
                        dec_ca_ow, dec_ca_ob, dec_n2_w, dec_n2_b);
        else if (ntokF <= 16)
            ffn_pass<2>(s, e, wb, L, gi, w3, flane, lane, hf*2,
                        dec_ca_ow, dec_ca_ob, dec_n2_w, dec_n2_b);
        else
            ffn_pass<4>(s, e, wb, L, gi, w3, flane, lane, hf*4,
                        dec_ca_ow, dec_ca_ob, dec_n2_w, dec_n2_b);
    };

    // ------ stage 32KB half hs of layer L (wv15 only) ------
    auto STAGE = [&](int L, int hs) {
        const int wi = (L < 12) ? L : 12 + (L - 12) % 12;
        const float4* sp = w_all + (size_t)wi*4096 + hs*2048;
        float4* dp = s.wbuf[L & 1] + hs*2048;
        #pragma unroll 8
        for (int j = 0; j < 32; ++j)
            dp[j*64 + lane] = sp[j*64 + lane];
    };

    // ------ main pipelined loop ------
    for (int g = 0; g <= 384; ++g) {
        // s0
        if (wv < 3)       { if (g < 384) P1(g, 0, MA0,MA1,MA2, OA0,OA1,OA2, EA0,EA1,EA2); }
        else if (wv < 15) { if (g >= 1)  FFNH(g - 1, 1, 0); }
        __syncthreads();
        // s1
        if (wv < 3)       { if (g < 384) P2(g, 0); }
        else if (wv < 15) { if (g >= 1)  FFNH(g - 1, 1, 1); }
        __syncthreads();
        if (g == 384) break;
        // s2
        if (wv < 3)       P1(g, 1, MB0,MB1,MB2, OB0,OB1,OB2, EB0,EB1,EB2);
        else if (wv < 15) FFNH(g, 0, 0);
        else              { if (g + 1 <= 383) STAGE(g + 1, 0); }
        __syncthreads();
        // s3
        if (wv < 3)       P2(g, 1);
        else if (wv < 15) FFNH(g, 0, 1);
        else              { if (g + 1 <= 383) STAGE(g + 1, 1); }
        __syncthreads();
    }

    // ---- final token-31 folds + output writes (wave 0 holds both O sets)
    if (wv == 0) {
        if (q == 31) {
            {
                float Xp0, Xp1, Xp2;
                xfrom(s, 0, 31, 383, dec_ca_ow, dec_ca_ob, dec_n2_w, dec_n2_b,
                      Xp0, Xp1, Xp2);
                float f0 = fr3(s.fred[0][31][0]);
                float f1 = fr3(s.fred[0][31][1]);
                float f2 = fr3(s.fred[0][31][2]);
                float o0, o1, o2;
                ln3s(Xp0 + f0 + dec_l2_b[33], Xp1 + f1 + dec_l2_b[34],
                     Xp2 + f2 + dec_l2_b[35], dec_n3_w + 33, dec_n3_b + 33,
                     o0, o1, o2);
                ln3s(o0, o1, o2, dec_nf_w, dec_nf_b, OA0, OA1, OA2);
            }
            {
                float Xp0, Xp1, Xp2;
                xfrom(s, 1, 31, 383, dec_ca_ow, dec_ca_ob, dec_n2_w, dec_n2_b,
                      Xp0, Xp1, Xp2);
                float f0 = fr3(s.fred[1][31][0]);
                float f1 = fr3(s.fred[1][31][1]);
                float f2 = fr3(s.fred[1][31][2]);
                float o0, o1, o2;
                ln3s(Xp0 + f0 + dec_l2_b[33], Xp1 + f1 + dec_l2_b[34],
                     Xp2 + f2 + dec_l2_b[35], dec_n3_w + 33, dec_n3_b + 33,
                     o0, o1, o2);
                ln3s(o0, o1, o2, dec_nf_w, dec_nf_b, OB0, OB1, OB2);
            }
        }
        if (lane < 32) {
            out[b0*96 +  0 + q] = OA0;
            out[b0*96 + 32 + q] = OA1;
            out[b0*96 + 64 + q] = OA2;
            out[(b0+1)*96 +  0 + q] = OB0;
            out[(b0+1)*96 + 32 + q] = OB1;
            out[(b0+1)*96 + 64 + q] = OB2;
        }
    }
}

extern "C" void kernel_launch(void* const* d_in, const int* in_sizes, int n_in,
                              void* d_out, int out_size, void* d_ws, size_t ws_size,
                              hipStream_t stream) {
    const float* src      = (const float*)d_in[0];
    const float* angle    = (const float*)d_in[1];
    const float* enc_sa_w = (const float*)d_in[2];
    const float* enc_sa_b = (const float*)d_in[3];
    const float* enc_sa_ow= (const float*)d_in[4];
    const float* enc_sa_ob= (const float*)d_in[5];
    const float* enc_l1_w = (const float*)d_in[6];
    const float* enc_l1_b = (const float*)d_in[7];
    const float* enc_l2_w = (const float*)d_in[8];
    const float* enc_l2_b = (const float*)d_in[9];
    const float* enc_n1_w = (const float*)d_in[10];
    const float* enc_n1_b = (const float*)d_in[11];
    const float* enc_n2_w = (const float*)d_in[12];
    const float* enc_n2_b = (const float*)d_in[13];
    const float* enc_nf_w = (const float*)d_in[14];
    const float* enc_nf_b = (const float*)d_in[15];
    const float* dec_sa_w = (const float*)d_in[16];
    const float* dec_sa_b = (const float*)d_in[17];
    const float* dec_sa_ow= (const float*)d_in[18];
    const float* dec_sa_ob= (const float*)d_in[19];
    const float* dec_ca_w = (const float*)d_in[20];
    const float* dec_ca_b = (const float*)d_in[21];
    const float* dec_ca_ow= (const float*)d_in[22];
    const float* dec_ca_ob= (const float*)d_in[23];
    const float* dec_l1_w = (const float*)d_in[24];
    const float* dec_l1_b = (const float*)d_in[25];
    const float* dec_l2_w = (const float*)d_in[26];
    const float* dec_l2_b = (const float*)d_in[27];
    const float* dec_n1_w = (const float*)d_in[28];
    const float* dec_n1_b = (const float*)d_in[29];
    const float* dec_n2_w = (const float*)d_in[30];
    const float* dec_n2_b = (const float*)d_in[31];
    const float* dec_n3_w = (const float*)d_in[32];
    const float* dec_n3_b = (const float*)d_in[33];
    const float* dec_nf_w = (const float*)d_in[34];
    const float* dec_nf_b = (const float*)d_in[35];

    float4* w_all = (float4*)d_ws;

    prepack_kernel<<<(24 * 1024 + 255) / 256, 256, 0, stream>>>(
        enc_l1_w, enc_l1_b, enc_l2_w,
        dec_l1_w, dec_l1_b, dec_l2_w,
        w_all);

    seq_kernel<<<NB/2, 1024, 0, stream>>>(
        src, angle,
        enc_sa_w, enc_sa_b, enc_sa_ow, enc_sa_ob, enc_l2_b,
        enc_n1_w, enc_n1_b, enc_n2_w, enc_n2_b, enc_nf_w, enc_nf_b,
        dec_sa_w, dec_sa_b, dec_sa_ow, dec_sa_ob,
        dec_ca_w, dec_ca_b, dec_ca_ow, dec_ca_ob, dec_l2_b,
        dec_n1_w, dec_n1_b, dec_n2_w, dec_n2_b, dec_n3_w, dec_n3_b,
        dec_nf_w, dec_nf_b,
        (const float4*)w_all,
        (float*)d_out);
}

// Round 8
// 1926.021 us; speedup vs baseline: 2.6561x; 2.6561x over previous
//
#include <hip/hip_runtime.h>
#include <math.h>

#define FF 2048
#define NL 12
#define NB 16
#define TT 32
#define EPS 1e-5f
#define LOG2E 1.44269504088896f

#if __has_builtin(__builtin_amdgcn_exp2f)
#define EXP2(x) __builtin_amdgcn_exp2f(x)
#else
#define EXP2(x) exp2f(x)
#endif

typedef float v2f __attribute__((ext_vector_type(2)));
__device__ __forceinline__ v2f mk2(float x){ v2f r; r.x = x; r.y = x; return r; }

// ---------------------------------------------------------------------------
// Prepack into d_ws as w_all[24][4096] float4, f-PAIRED for packed math:
//   [0..1023]    A0[fp] = {w0[2fp],w0[2fp+1], w1[2fp],w1[2fp+1]}
//   [1024..2047] A1[fp] = {w2[2fp],w2[2fp+1], b[2fp], b[2fp+1]}
//   [2048..3071] C0[fp] = {u0[2fp],u0[2fp+1], u1[2fp],u1[2fp+1]}
//   [3072..4095] C1[fp] = {u2[2fp],u2[2fp+1], 0, 0}
// ---------------------------------------------------------------------------
__global__ __launch_bounds__(256) void prepack_kernel(
    const float* __restrict__ enc_l1_w, const float* __restrict__ enc_l1_b,
    const float* __restrict__ enc_l2_w,
    const float* __restrict__ dec_l1_w, const float* __restrict__ dec_l1_b,
    const float* __restrict__ dec_l2_w,
    float4* __restrict__ w_all)
{
    int idx = blockIdx.x * blockDim.x + threadIdx.x;
    if (idx >= 24 * 1024) return;
    int lay = idx >> 10;
    int fp  = idx & 1023;
    int f0  = 2*fp, f1 = 2*fp + 1;
    const float *w1, *b1, *w2;
    if (lay < NL) {
        w1 = enc_l1_w + (size_t)lay * FF * 3;
        b1 = enc_l1_b + (size_t)lay * FF;
        w2 = enc_l2_w + (size_t)lay * 3 * FF;
    } else {
        int l = lay - NL;
        w1 = dec_l1_w + (size_t)l * FF * 3;
        b1 = dec_l1_b + (size_t)l * FF;
        w2 = dec_l2_w + (size_t)l * 3 * FF;
    }
    float4* base = w_all + (size_t)lay * 4096;
    base[fp]        = make_float4(w1[f0*3+0], w1[f1*3+0], w1[f0*3+1], w1[f1*3+1]);
    base[1024 + fp] = make_float4(w1[f0*3+2], w1[f1*3+2], b1[f0],     b1[f1]);
    base[2048 + fp] = make_float4(w2[f0],     w2[f1],     w2[FF+f0],  w2[FF+f1]);
    base[3072 + fp] = make_float4(w2[2*FF+f0], w2[2*FF+f1], 0.f, 0.f);
}

// ---------------------------------------------------------------------------
// Main kernel: one block per batch element, 1024 threads (16 waves).
// R0 structure (best verified: 1788 us rocprof) + 2 local trims:
//  - decoder SA masked-block skip (bitwise identical, shorter exp2 chain)
//  - s_setprio(1) on the attn critical-path waves in P1/P2/P3 (T5 regime:
//    attn waves vs staging waves = role diversity; +4-7% measured on attn)
// ---------------------------------------------------------------------------
struct __align__(16) SharedMem {
    float4 wbuf[2][4096];  // double-buffered layer weights (128 KB)
    float4 x4[TT];         // activations
    float4 fred[TT][3];    // FFN partials: [t][d] = 4 per-wave-group sums
    float4 outst[TT];      // decoder predictions
    float4 mem4[TT];       // encoder output
    float  kk[3][TT];      // self-attn keys, head-major
    float  vv[3][TT];      // self-attn values
    float4 oo[TT];         // SA attention outputs {h0,h1,h2,-}
    float4 oo2[TT];        // CA attention outputs {h0,h1,h2,-}
    float  ck[NL][3][TT];  // cross-attn keys per decoder layer
    float  cv[NL][3][TT];  // cross-attn values
};

__device__ __forceinline__ void ln3s(float y0, float y1, float y2,
    const float* __restrict__ w, const float* __restrict__ b,
    float& o0, float& o1, float& o2)
{
    float m  = (y0 + y1 + y2) * (1.0f / 3.0f);
    float d0 = y0 - m, d1 = y1 - m, d2 = y2 - m;
    float v  = (d0*d0 + d1*d1 + d2*d2) * (1.0f / 3.0f);
    float r  = __builtin_amdgcn_rsqf(v + EPS);
    o0 = d0 * r * w[0] + b[0];
    o1 = d1 * r * w[1] + b[1];
    o2 = d2 * r * w[2] + b[2];
}

template<int CTRL>
__device__ __forceinline__ float dpp_add(float v)
{
    int sh = __builtin_amdgcn_update_dpp(0, __float_as_int(v), CTRL, 0xF, 0xF, true);
    return v + __int_as_float(sh);
}

__device__ __forceinline__ float wave_sum64(float v)
{
    v = dpp_add<0x111>(v);
    v = dpp_add<0x112>(v);
    v = dpp_add<0x114>(v);
    v = dpp_add<0x118>(v);
    v = dpp_add<0x142>(v);
    v = dpp_add<0x143>(v);
    return v;   // valid in lane 63
}

__device__ __forceinline__ float sum4(float4 r)
{
    return (r.x + r.y) + (r.z + r.w);
}

// Halved-range softmax-attention: lanes 0-31 handle keys 0..15, lanes 32-63
// keys 16..31; partials combined via shfl_xor(32). qs has log2e folded.
// MASK: whole 4-key blocks skipped when jbase >= ntok (bitwise identical to
// running them: masked terms contributed exactly 0), plus per-key mask +
// representative multiplicity.
template<bool MASK>
__device__ __forceinline__ float attn_half(float qs,
    const float* __restrict__ k, const float* __restrict__ v,
    int half, int ntok, int rep, float repw)
{
    const float4* k4 = (const float4*)k;
    const float4* v4 = (const float4*)v;
    float den0 = 0.f, den1 = 0.f, nv0 = 0.f, nv1 = 0.f;
    #pragma unroll
    for (int jb = 0; jb < 4; ++jb) {
        const int jbase = half*16 + jb*4;
        if (!MASK || jbase < ntok) {
            float4 kq = k4[half*4 + jb];
            float4 vq = v4[half*4 + jb];
            const float kj[4] = {kq.x, kq.y, kq.z, kq.w};
            const float vj[4] = {vq.x, vq.y, vq.z, vq.w};
            #pragma unroll
            for (int u = 0; u < 4; ++u) {
                float w = EXP2(qs * kj[u]);
                if (MASK) {
                    const int j = jbase + u;
                    w = (j < ntok) ? w : 0.f;
                    w = (j == rep) ? w * repw : w;
                }
                if (jb & 1) { den1 += w; nv1 = fmaf(w, vj[u], nv1); }
                else        { den0 += w; nv0 = fmaf(w, vj[u], nv0); }
            }
        }
    }
    float den = den0 + den1;
    float nv  = nv0 + nv1;
    den += __shfl_xor(den, 32, 64);
    nv  += __shfl_xor(nv , 32, 64);
    return nv * __builtin_amdgcn_rcpf(den);
}

// FFN: 4 token groups x 256 f-lanes, 4 f-pairs per thread, packed fp32 math
// (v_pk_fma_f32), weights from LDS, DPP reduction + lane-63 store.
template<int NII>
__device__ __forceinline__ void ffn_body(SharedMem& s, int tid,
    const float4* __restrict__ wb)
{
    const int flane = tid & 255;
    const int g     = tid >> 8;
    const int w4    = (tid >> 6) & 3;
    const int lane  = tid & 63;
    const v2f z2 = {0.f, 0.f};
    float X0[NII], X1[NII], X2[NII];
    v2f ac0[NII], ac1[NII], ac2[NII];
    #pragma unroll
    for (int ii = 0; ii < NII; ++ii) {
        float4 xt = s.x4[g + 4*ii];
        X0[ii] = xt.x; X1[ii] = xt.y; X2[ii] = xt.z;
        ac0[ii] = z2; ac1[ii] = z2; ac2[ii] = z2;
    }
    #pragma unroll
    for (int jp = 0; jp < 4; ++jp) {
        const int fp = flane + 256*jp;
        float4 A0 = wb[fp], A1 = wb[1024+fp];
        float4 C0 = wb[2048+fp], C1 = wb[3072+fp];
        v2f ax = {A0.x, A0.y}, ay = {A0.z, A0.w};
        v2f az = {A1.x, A1.y}, ab = {A1.z, A1.w};
        v2f cx = {C0.x, C0.y}, cy = {C0.z, C0.w};
        v2f cz = {C1.x, C1.y};
        #pragma unroll
        for (int ii = 0; ii < NII; ++ii) {
            v2f h2 = __builtin_elementwise_fma(ax, mk2(X0[ii]),
                     __builtin_elementwise_fma(ay, mk2(X1[ii]),
                     __builtin_elementwise_fma(az, mk2(X2[ii]), ab)));
            h2 = __builtin_elementwise_max(h2, z2);
            ac0[ii] = __builtin_elementwise_fma(cx, h2, ac0[ii]);
            ac1[ii] = __builtin_elementwise_fma(cy, h2, ac1[ii]);
            ac2[ii] = __builtin_elementwise_fma(cz, h2, ac2[ii]);
        }
    }
    #pragma unroll
    for (int ii = 0; ii < NII; ++ii) {
        const int t = g + 4*ii;
        float r0 = wave_sum64(ac0[ii].x + ac0[ii].y);
        float r1 = wave_sum64(ac1[ii].x + ac1[ii].y);
        float r2 = wave_sum64(ac2[ii].x + ac2[ii].y);
        if (lane == 63) {
            ((float*)&s.fred[t][0])[w4] = r0;
            ((float*)&s.fred[t][1])[w4] = r1;
            ((float*)&s.fred[t][2])[w4] = r2;
        }
    }
}

// One transformer layer (R0 phase structure).
// P1: waves 0-2 combine+SA->oo | waves 3-15 prefetch half A.   barrier
// P2: waves 0-2 SA out-proj + LN1 -> B (redundant); if CA: CA -> oo2; else
//     wave0 writes x4. | waves 3-15 prefetch half B.           barrier
// P3 (CA only): wave0 CA out-proj + LN2 -> x4.                 barrier
// P4: FFN (all 16 waves).                                      barrier
template<bool HAS_CA, bool MASK_SA>
__device__ __forceinline__ void run_layer(SharedMem& s, int tid,
    int ntok, int rep, float repw, int do_combine, int p,
    const float4* __restrict__ nw,
    const float* __restrict__ saw, const float* __restrict__ sab,
    const float* __restrict__ saow, const float* __restrict__ saob,
    const float* __restrict__ n1w, const float* __restrict__ n1b,
    const float* __restrict__ caw, const float* __restrict__ cab,
    const float* __restrict__ caow, const float* __restrict__ caob,
    const float* __restrict__ n2w, const float* __restrict__ n2b,
    const float* __restrict__ ckh, const float* __restrict__ cvh,
    const float* __restrict__ pl2b, const float* __restrict__ pnw,
    const float* __restrict__ pnb)
{
    const int wv   = tid >> 6;
    const int lane = tid & 63;
    const int q    = lane & 31;
    const int half = lane >> 5;
    float X0 = 0.f, X1 = 0.f, X2 = 0.f;
    float B0 = 0.f, B1 = 0.f, B2 = 0.f;

    // ---------------- P1 ----------------
    if (wv >= 3) {
        for (int k = tid - 192; k < 2048; k += 832)
            s.wbuf[p ^ 1][k] = nw[k];
    } else {
        __builtin_amdgcn_s_setprio(1);
        const int h = wv;
        float4 xa = s.x4[q];
        if (do_combine) {
            float f0 = sum4(s.fred[q][0]);
            float f1 = sum4(s.fred[q][1]);
            float f2 = sum4(s.fred[q][2]);
            ln3s(xa.x + f0 + pl2b[0], xa.y + f1 + pl2b[1],
                 xa.z + f2 + pl2b[2], pnw, pnb, X0, X1, X2);
        } else { X0 = xa.x; X1 = xa.y; X2 = xa.z; }
        if (lane < 32 && q < ntok) {
            s.kk[h][q] = sab[3+h] + saw[9+3*h]*X0  + saw[10+3*h]*X1 + saw[11+3*h]*X2;
            s.vv[h][q] = sab[6+h] + saw[18+3*h]*X0 + saw[19+3*h]*X1 + saw[20+3*h]*X2;
        }
        float qv = (sab[h] + saw[3*h]*X0 + saw[3*h+1]*X1 + saw[3*h+2]*X2) * LOG2E;
        float o = attn_half<MASK_SA>(qv, s.kk[h], s.vv[h], half, ntok, rep, repw);
        if (lane < 32 && q < ntok) ((float*)&s.oo[q])[h] = o;
        __builtin_amdgcn_s_setprio(0);
    }
    __syncthreads();   // bar1
    // ---------------- P2 ----------------
    if (wv >= 3) {
        for (int k = 2048 + tid - 192; k < 4096; k += 832)
            s.wbuf[p ^ 1][k] = nw[k];
    } else {
        __builtin_amdgcn_s_setprio(1);
        const int h = wv;
        float4 ov = s.oo[q];
        float y0 = X0 + saob[0] + saow[0]*ov.x + saow[1]*ov.y + saow[2]*ov.z;
        float y1 = X1 + saob[1] + saow[3]*ov.x + saow[4]*ov.y + saow[5]*ov.z;
        float y2 = X2 + saob[2] + saow[6]*ov.x + saow[7]*ov.y + saow[8]*ov.z;
        ln3s(y0, y1, y2, n1w, n1b, B0, B1, B2);
        if (!HAS_CA) {
            if (wv == 0 && lane < 32 && q < ntok)
                s.x4[q] = make_float4(B0, B1, B2, 0.f);
        } else {
            float cqv = (cab[h] + caw[3*h]*B0 + caw[3*h+1]*B1 + caw[3*h+2]*B2) * LOG2E;
            float oc = attn_half<false>(cqv, ckh + h*TT, cvh + h*TT, half, TT, -1, 1.f);
            if (lane < 32 && q < ntok) ((float*)&s.oo2[q])[h] = oc;
        }
        __builtin_amdgcn_s_setprio(0);
    }
    __syncthreads();   // bar2
    if (HAS_CA) {
        // ---------------- P3: wave0 CA out-proj + LN2 -> x4 ----------------
        if (wv == 0 && lane < 32 && q < ntok) {
            __builtin_amdgcn_s_setprio(1);
            float4 cv2 = s.oo2[q];
            float y0 = B0 + caob[0] + caow[0]*cv2.x + caow[1]*cv2.y + caow[2]*cv2.z;
            float y1 = B1 + caob[1] + caow[3]*cv2.x + caow[4]*cv2.y + caow[5]*cv2.z;
            float y2 = B2 + caob[2] + caow[6]*cv2.x + caow[7]*cv2.y + caow[8]*cv2.z;
            float a0, a1, a2;
            ln3s(y0, y1, y2, n2w, n2b, a0, a1, a2);
            s.x4[q] = make_float4(a0, a1, a2, 0.f);
            __builtin_amdgcn_s_setprio(0);
        }
        __syncthreads();   // bar3
    }
    // ---------------- P4: FFN ----------------
    const float4* wb = s.wbuf[p];
    if (ntok <= 8)       ffn_body<2>(s, tid, wb);
    else if (ntok <= 16) ffn_body<4>(s, tid, wb);
    else                 ffn_body<8>(s, tid, wb);
    __syncthreads();   // bar4
}

__global__ __launch_bounds__(1024, 4) void seq_kernel(
    const float* __restrict__ src, const float* __restrict__ angle,
    const float* __restrict__ enc_sa_w, const float* __restrict__ enc_sa_b,
    const float* __restrict__ enc_sa_ow, const float* __restrict__ enc_sa_ob,
    const float* __restrict__ enc_l2_b,
    const float* __restrict__ enc_n1_w, const float* __restrict__ enc_n1_b,
    const float* __restrict__ enc_n2_w, const float* __restrict__ enc_n2_b,
    const float* __restrict__ enc_nf_w, const float* __restrict__ enc_nf_b,
    const float* __restrict__ dec_sa_w, const float* __restrict__ dec_sa_b,
    const float* __restrict__ dec_sa_ow, const float* __restrict__ dec_sa_ob,
    const float* __restrict__ dec_ca_w, const float* __restrict__ dec_ca_b,
    const float* __restrict__ dec_ca_ow, const float* __restrict__ dec_ca_ob,
    const float* __restrict__ dec_l2_b,
    const float* __restrict__ dec_n1_w, const float* __restrict__ dec_n1_b,
    const float* __restrict__ dec_n2_w, const float* __restrict__ dec_n2_b,
    const float* __restrict__ dec_n3_w, const float* __restrict__ dec_n3_b,
    const float* __restrict__ dec_nf_w, const float* __restrict__ dec_nf_b,
    const float4* __restrict__ w_all,
    float* __restrict__ out)
{
    __shared__ SharedMem s;
    const int tid = threadIdx.x;
    const int b   = blockIdx.x;

    // ---- init: stage encoder layer 0 weights + build input
    for (int k = tid; k < 4096; k += 1024)
        s.wbuf[0][k] = w_all[k];
    if (tid < TT) {
        float x0 = src[b*64 + tid];
        float x1 = src[b*64 + 32 + tid];
        float x2 = angle[b];
        s.x4[tid] = make_float4(x0, x1, x2, 0.f);
        if (tid == 0) s.outst[0] = make_float4(x0, x1, x2, 0.f);
    }
    __syncthreads();

    int lp = 0;
    // ---- encoder
    for (int i = 0; i < NL; ++i) {
        const float4* nw = w_all + (size_t)((i < 11) ? (i + 1) : 12) * 4096;
        const int pi = (i > 0) ? (i - 1) : 0;
        run_layer<false, false>(s, tid, TT, -1, 1.f, i > 0, lp & 1, nw,
            enc_sa_w + i*27, enc_sa_b + i*9, enc_sa_ow + i*9, enc_sa_ob + i*3,
            enc_n1_w + i*3, enc_n1_b + i*3,
            nullptr, nullptr, nullptr, nullptr, nullptr, nullptr,
            nullptr, nullptr,
            enc_l2_b + pi*3, enc_n2_w + pi*3, enc_n2_b + pi*3);
        ++lp;
    }
    // encoder tail: combine layer 11 + final LN -> mem; rebuild x for step 1
    if (tid < 32) {
        float4 xa = s.x4[tid];
        float f0 = sum4(s.fred[tid][0]);
        float f1 = sum4(s.fred[tid][1]);
        float f2 = sum4(s.fred[tid][2]);
        float o0, o1, o2, m0, m1, m2;
        ln3s(xa.x + f0 + enc_l2_b[33], xa.y + f1 + enc_l2_b[34],
             xa.z + f2 + enc_l2_b[35], enc_n2_w + 33, enc_n2_b + 33, o0, o1, o2);
        ln3s(o0, o1, o2, enc_nf_w, enc_nf_b, m0, m1, m2);
        s.mem4[tid] = make_float4(m0, m1, m2, 0.f);
        s.x4[tid]   = (tid == 0) ? s.outst[0] : make_float4(0.f, 0.f, 0.f, 0.f);
    }
    __syncthreads();

    // ---- precompute cross-attn K,V for all decoder layers (head-major)
    for (int idx = tid; idx < NL * 96; idx += 1024) {
        const int lyr = idx / 96;
        const int r   = idx - lyr * 96;
        const int hh  = r >> 5;
        const int t   = r & 31;
        const float* w  = dec_ca_w + lyr*27;
        const float* bb = dec_ca_b + lyr*9;
        float4 mr = s.mem4[t];
        s.ck[lyr][hh][t] = bb[3+hh] + w[(3+hh)*3]*mr.x + w[(3+hh)*3+1]*mr.y + w[(3+hh)*3+2]*mr.z;
        s.cv[lyr][hh][t] = bb[6+hh] + w[(6+hh)*3]*mr.x + w[(6+hh)*3+1]*mr.y + w[(6+hh)*3+2]*mr.z;
    }
    __syncthreads();

    // ---- autoregressive decode with zero-token collapse:
    // tokens 0..t-1 real, token t = representative of 32-t identical zeros
    // (softmax multiplicity 32-t); pred[t] = representative output.
    for (int t = 1; t < TT; ++t) {
        const int ntok = t + 1;
        for (int i = 0; i < NL; ++i) {
            const float4* nw = w_all + (size_t)(12 + ((i < 11) ? (i + 1) : 0)) * 4096;
            const int pi = (i > 0) ? (i - 1) : 0;
            run_layer<true, true>(s, tid, ntok, t, (float)(TT - t), i > 0, lp & 1, nw,
                dec_sa_w + i*27, dec_sa_b + i*9, dec_sa_ow + i*9, dec_sa_ob + i*3,
                dec_n1_w + i*3, dec_n1_b + i*3,
                dec_ca_w + i*27, dec_ca_b + i*9, dec_ca_ow + i*9, dec_ca_ob + i*3,
                dec_n2_w + i*3, dec_n2_b + i*3,
                &s.ck[i][0][0], &s.cv[i][0][0],
                dec_l2_b + pi*3, dec_n3_w + pi*3, dec_n3_b + pi*3);
            ++lp;
        }
        // tail: combine layer 11 for token t -> outst[t]; rebuild x
        if (tid < 32) {
            if (tid == 0) {
                float4 xa = s.x4[t];
                float f0 = sum4(s.fred[t][0]);
                float f1 = sum4(s.fred[t][1]);
                float f2 = sum4(s.fred[t][2]);
                float o0, o1, o2, p0, p1, p2;
                ln3s(xa.x + f0 + dec_l2_b[33], xa.y + f1 + dec_l2_b[34],
                     xa.z + f2 + dec_l2_b[35], dec_n3_w + 33, dec_n3_b + 33,
                     o0, o1, o2);
                ln3s(o0, o1, o2, dec_nf_w, dec_nf_b, p0, p1, p2);
                s.outst[t] = make_float4(p0, p1, p2, 0.f);
            }
            s.x4[tid] = (tid <= t) ? s.outst[tid] : make_float4(0.f, 0.f, 0.f, 0.f);
        }
        __syncthreads();
    }

    // ---- write output: out[b, c, t]
    if (tid < TT) {
        float4 o = s.outst[tid];
        out[b*96 +  0 + tid] = o.x;
        out[b*96 + 32 + tid] = o.y;
        out[b*96 + 64 + tid] = o.z;
    }
}

extern "C" void kernel_launch(void* const* d_in, const int* in_sizes, int n_in,
                              void* d_out, int out_size, void* d_ws, size_t ws_size,
                              hipStream_t stream) {
    const float* src      = (const float*)d_in[0];
    const float* angle    = (const float*)d_in[1];
    const float* enc_sa_w = (const float*)d_in[2];
    const float* enc_sa_b = (const float*)d_in[3];
    const float* enc_sa_ow= (const float*)d_in[4];
    const float* enc_sa_ob= (const float*)d_in[5];
    const float* enc_l1_w = (const float*)d_in[6];
    const float* enc_l1_b = (const float*)d_in[7];
    const float* enc_l2_w = (const float*)d_in[8];
    const float* enc_l2_b = (const float*)d_in[9];
    const float* enc_n1_w = (const float*)d_in[10];
    const float* enc_n1_b = (const float*)d_in[11];
    const float* enc_n2_w = (const float*)d_in[12];
    const float* enc_n2_b = (const float*)d_in[13];
    const float* enc_nf_w = (const float*)d_in[14];
    const float* enc_nf_b = (const float*)d_in[15];
    const float* dec_sa_w = (const float*)d_in[16];
    const float* dec_sa_b = (const float*)d_in[17];
    const float* dec_sa_ow= (const float*)d_in[18];
    const float* dec_sa_ob= (const float*)d_in[19];
    const float* dec_ca_w = (const float*)d_in[20];
    const float* dec_ca_b = (const float*)d_in[21];
    const float* dec_ca_ow= (const float*)d_in[22];
    const float* dec_ca_ob= (const float*)d_in[23];
    const float* dec_l1_w = (const float*)d_in[24];
    const float* dec_l1_b = (const float*)d_in[25];
    const float* dec_l2_w = (const float*)d_in[26];
    const float* dec_l2_b = (const float*)d_in[27];
    const float* dec_n1_w = (const float*)d_in[28];
    const float* dec_n1_b = (const float*)d_in[29];
    const float* dec_n2_w = (const float*)d_in[30];
    const float* dec_n2_b = (const float*)d_in[31];
    const float* dec_n3_w = (const float*)d_in[32];
    const float* dec_n3_b = (const float*)d_in[33];
    const float* dec_nf_w = (const float*)d_in[34];
    const float* dec_nf_b = (const float*)d_in[35];

    float4* w_all = (float4*)d_ws;

    prepack_kernel<<<(24 * 1024 + 255) / 256, 256, 0, stream>>>(
        enc_l1_w, enc_l1_b, enc_l2_w,
        dec_l1_w, dec_l1_b, dec_l2_w,
        w_all);

    seq_kernel<<<NB, 1024, 0, stream>>>(
        src, angle,
        enc_sa_w, enc_sa_b, enc_sa_ow, enc_sa_ob, enc_l2_b,
        enc_n1_w, enc_n1_b, enc_n2_w, enc_n2_b, enc_nf_w, enc_nf_b,
        dec_sa_w, dec_sa_b, dec_sa_ow, dec_sa_ob,
        dec_ca_w, dec_ca_b, dec_ca_ow, dec_ca_ob, dec_l2_b,
        dec_n1_w, dec_n1_b, dec_n2_w, dec_n2_b, dec_n3_w, dec_n3_b,
        dec_nf_w, dec_nf_b,
        (const float4*)w_all,
        (float*)d_out);
}